// Round 3
// baseline (182.517 us; speedup 1.0000x reference)
//
#include <hip/hip_runtime.h>

// VectorQuantizer: B=65536 rows, D=256, K=1024 codes.
// d_in[0] = inputs (B,D) fp32 ; d_in[1] = W (K,D) fp32
// d_out = [quantized_st (B*D)] [loss] [perplexity]  (fp32)
//
// R2: 64-row blocks, 4 blocks/CU -> occupancy 41%, vq_main 82us, all pipes
// <25% => still latency-bound. R3: 32-row blocks -> LDS 18.2 KB ->
// 8 blocks/CU (thread-capped, 32 waves/CU). acc/best halve so VGPR<=64
// holds at __launch_bounds__(256,8). Whp L2 traffic doubles (1 GB, ~30us
// aggregate L2) - predicted still below the new runtime. Memset folded
// into vq_wconv block 0 (one fewer dispatch).

using h16   = _Float16;
using h16x8 = __attribute__((ext_vector_type(8))) _Float16;
using f32x4 = __attribute__((ext_vector_type(4))) float;

#define W_SCALE 1024.0f          // keep fp16 W out of denormal range
#define W_UNSCALE2 0.001953125f  // 2 / 1024, exact power of two
#define XS_STRIDE 264            // 256 + 8 halves pad (row stride 528B -> 2-way bank alias only)

// ---------------- kernel 1: pack W -> fp16 fragment-order + ||w||^2 + ws zero ----------------
// Packed layout: Whp[((tile*8 + ks)*64 + quad*16 + lm)*8 + j]
//   = W_scaled[code = tile*16 + lm][d = ks*32 + quad*8 + j]
__global__ __launch_bounds__(64) void vq_wconv(const float* __restrict__ W,
                                               h16* __restrict__ Whp,
                                               float* __restrict__ wws,
                                               int* __restrict__ zero_base) {
  const int t = threadIdx.x;
  if (blockIdx.x == 0) {
    // zero loss_sum (1 f32 @ 0) + counts (1024 i32 @ 256B): 1088 dwords over [0,4352)
#pragma unroll
    for (int i = t; i < 1088; i += 64) zero_base[i] = 0;
  }
  const int code = blockIdx.x * 2 + (t >> 5);  // 2 codes per block
  const int j = t & 31;                        // d-group of 8
  const int d0 = j * 8;
  f32x4 v0 = *(const f32x4*)(W + (size_t)code * 256 + d0);
  f32x4 v1 = *(const f32x4*)(W + (size_t)code * 256 + d0 + 4);
  h16x8 h;
  h[0] = (h16)(v0[0] * W_SCALE); h[1] = (h16)(v0[1] * W_SCALE);
  h[2] = (h16)(v0[2] * W_SCALE); h[3] = (h16)(v0[3] * W_SCALE);
  h[4] = (h16)(v1[0] * W_SCALE); h[5] = (h16)(v1[1] * W_SCALE);
  h[6] = (h16)(v1[2] * W_SCALE); h[7] = (h16)(v1[3] * W_SCALE);
  const int tile = code >> 4, ks = j >> 2, quad = j & 3, lm = code & 15;
  *(h16x8*)(Whp + (size_t)(((tile * 8 + ks) * 64 + quad * 16 + lm) * 8)) = h;
  float ss = v0[0] * v0[0] + v0[1] * v0[1] + v0[2] * v0[2] + v0[3] * v0[3]
           + v1[0] * v1[0] + v1[1] * v1[1] + v1[2] * v1[2] + v1[3] * v1[3];
#pragma unroll
  for (int m = 1; m <= 16; m <<= 1) ss += __shfl_xor(ss, m);  // within 32-lane half
  if (j == 0) wws[code] = ss;
}

// ---------------- kernel 2: fused scores + argmin + output + loss + histogram ----------------
// Block: 32 rows x all 1024 codes. 256 threads = 4 waves, 8 blocks/CU.
// Per chunk (128 codes): wave w covers n-tiles {chunk*8 + w*2, +1}.
// mfma_f32_16x16x32_f16: A[m=lm][k=quad*8+j], B[k=quad*8+j][n=lm],
//                        D[row=quad*4+reg][col=lm]
__global__ __launch_bounds__(256, 8) void vq_main(const float* __restrict__ X,
                                                  const h16* __restrict__ Whp,
                                                  const float* __restrict__ wws,
                                                  const float* __restrict__ W,
                                                  float* __restrict__ out,
                                                  float* __restrict__ loss_sum,
                                                  int* __restrict__ counts) {
  __shared__ h16 Xs[32 * XS_STRIDE];  // 16896 B
  __shared__ float redS[4 * 32];      // 512 B
  __shared__ int redC[4 * 32];        // 512 B
  __shared__ int sIdx[32];            // 128 B
  __shared__ float xnorm[32];         // 128 B   (total 18176 B -> 8 blocks/CU)
  const int tid = threadIdx.x;
  const int lane = tid & 63;
  const int wid = tid >> 6;
  const int lm = lane & 15;
  const int quad = lane >> 4;
  const int rowBase = blockIdx.x * 32;

  // stage X tile (32 rows x 256 d, fp32 -> fp16) + fp32 ||x||^2 per row.
  // 32 consecutive threads (one half-wave) cover one row.
#pragma unroll
  for (int it = 0; it < 4; ++it) {
    int q = it * 256 + tid;
    int r = q >> 5;
    int dp = (q & 31) << 3;
    const float* src = X + (size_t)(rowBase + r) * 256 + dp;
    f32x4 v0 = __builtin_nontemporal_load((const f32x4*)src);
    f32x4 v1 = __builtin_nontemporal_load((const f32x4*)src + 1);
    h16x8 h;
    h[0] = (h16)v0[0]; h[1] = (h16)v0[1]; h[2] = (h16)v0[2]; h[3] = (h16)v0[3];
    h[4] = (h16)v1[0]; h[5] = (h16)v1[1]; h[6] = (h16)v1[2]; h[7] = (h16)v1[3];
    *(h16x8*)(Xs + r * XS_STRIDE + dp) = h;
    float ss = v0[0] * v0[0] + v0[1] * v0[1] + v0[2] * v0[2] + v0[3] * v0[3]
             + v1[0] * v1[0] + v1[1] * v1[1] + v1[2] * v1[2] + v1[3] * v1[3];
#pragma unroll
    for (int m = 1; m <= 16; m <<= 1) ss += __shfl_xor(ss, m);  // within the 32-lane half
    if ((q & 31) == 0) xnorm[r] = ss;
  }
  __syncthreads();  // the ONLY barrier before the reduce

  // running best per row-slot: slot = mt*4+reg -> row = mt*16 + quad*4 + reg
  float bestS[8];
  int bestC[8];
#pragma unroll
  for (int s = 0; s < 8; ++s) { bestS[s] = 3.4e38f; bestC[s] = 0x7fffffff; }

  for (int chunk = 0; chunk < 8; ++chunk) {
    const int tbase = chunk * 8 + wid * 2;  // this wave's first n-tile
    const h16* bptr = Whp + (size_t)tbase * 4096 + lane * 8;
    float wn0 = wws[tbase * 16 + lm];        // hoisted: hides under MFMAs
    float wn1 = wws[tbase * 16 + 16 + lm];
    f32x4 acc[2][2];
#pragma unroll
    for (int mt = 0; mt < 2; ++mt)
#pragma unroll
      for (int nt = 0; nt < 2; ++nt) {
        f32x4 z = {0.0f, 0.0f, 0.0f, 0.0f};
        acc[mt][nt] = z;
      }

#pragma unroll 2
    for (int ks = 0; ks < 8; ++ks) {  // no barriers: B from L2, A from LDS
      h16x8 b0 = *(const h16x8*)(bptr + ks * 512);         // n-tile tbase
      h16x8 b1 = *(const h16x8*)(bptr + ks * 512 + 4096);  // n-tile tbase+1
      const int doff = ks * 32 + quad * 8;
#pragma unroll
      for (int mt = 0; mt < 2; ++mt) {
        h16x8 a = *(const h16x8*)(Xs + (mt * 16 + lm) * XS_STRIDE + doff);
        acc[mt][0] = __builtin_amdgcn_mfma_f32_16x16x32_f16(a, b0, acc[mt][0], 0, 0, 0);
        acc[mt][1] = __builtin_amdgcn_mfma_f32_16x16x32_f16(a, b1, acc[mt][1], 0, 0, 0);
      }
    }

    // epilogue: score = ||w||^2 - 2*dot ; fold into running best
#pragma unroll
    for (int nt = 0; nt < 2; ++nt) {
      int code = (tbase + nt) * 16 + lm;
      float wn = nt ? wn1 : wn0;
#pragma unroll
      for (int mt = 0; mt < 2; ++mt)
#pragma unroll
        for (int reg = 0; reg < 4; ++reg) {
          float s = fmaf(-W_UNSCALE2, acc[mt][nt][reg], wn);
          int slot = mt * 4 + reg;
          if (s < bestS[slot]) { bestS[slot] = s; bestC[slot] = code; }
        }
    }
  }

  // reduce across the 16 lanes of each quad (same rows, different codes)
#pragma unroll
  for (int m = 1; m <= 8; m <<= 1) {
#pragma unroll
    for (int s = 0; s < 8; ++s) {
      float os = __shfl_xor(bestS[s], m);
      int oc = __shfl_xor(bestC[s], m);
      if (os < bestS[s] || (os == bestS[s] && oc < bestC[s])) { bestS[s] = os; bestC[s] = oc; }
    }
  }
  if (lm == 0) {
#pragma unroll
    for (int s = 0; s < 8; ++s) {
      int row = (s >> 2) * 16 + quad * 4 + (s & 3);
      redS[wid * 32 + row] = bestS[s];
      redC[wid * 32 + row] = bestC[s];
    }
  }
  __syncthreads();
  if (wid == 0) {  // wave 0: final argmin per row + histogram + loss
    float lossv = 0.0f;
    if (lane < 32) {
      float b = 3.4e38f;
      int c = 0x7fffffff;
#pragma unroll
      for (int w = 0; w < 4; ++w) {
        float s = redS[w * 32 + lane];
        int cc = redC[w * 32 + lane];
        if (s < b || (s == b && cc < c)) { b = s; c = cc; }
      }
      sIdx[lane] = c;
      atomicAdd(&counts[c], 1);
      // ||x - w||^2 = ||x||^2 + (||w||^2 - 2 x.w) = xnorm + bestScore
      lossv = xnorm[lane] + b;
    }
#pragma unroll
    for (int m = 1; m <= 32; m <<= 1) lossv += __shfl_xor(lossv, m);
    if (lane == 0) atomicAdd(loss_sum, lossv);
  }
  __syncthreads();

  // output phase: out row = W[idx] (== x + sg(q-x) numerically). Wave w: rows w*8..+7.
  const int d4 = lane << 2;
#pragma unroll 2
  for (int i = 0; i < 8; ++i) {
    int row = wid * 8 + i;
    int idx = sIdx[row];
    f32x4 qv = *(const f32x4*)(W + (size_t)idx * 256 + d4);
    __builtin_nontemporal_store(qv, (f32x4*)(out + (size_t)(rowBase + row) * 256 + d4));
  }
}

// ---------------- kernel 3: loss + perplexity ----------------
__global__ __launch_bounds__(256) void vq_finalize(const int* __restrict__ counts,
                                                   const float* __restrict__ loss_sum,
                                                   float* __restrict__ out) {
  __shared__ float red[256];
  const int tid = threadIdx.x;
  float h = 0.0f;
#pragma unroll
  for (int k = tid; k < 1024; k += 256) {
    float p = (float)counts[k] * (1.0f / 65536.0f);
    h += p * logf(p + 1e-10f);
  }
  red[tid] = h;
  __syncthreads();
#pragma unroll
  for (int s = 128; s > 0; s >>= 1) {
    if (tid < s) red[tid] += red[tid + s];
    __syncthreads();
  }
  if (tid == 0) {
    out[16777216] = loss_sum[0] * (1.25f / 16777216.0f);  // (1+0.25)*mean((q-x)^2)
    out[16777217] = expf(-red[0]);
  }
}

// ---------------- launch ----------------
extern "C" void kernel_launch(void* const* d_in, const int* in_sizes, int n_in,
                              void* d_out, int out_size, void* d_ws, size_t ws_size,
                              hipStream_t stream) {
  (void)in_sizes; (void)n_in; (void)out_size; (void)ws_size;
  const float* X = (const float*)d_in[0];
  const float* W = (const float*)d_in[1];
  float* out = (float*)d_out;
  char* ws = (char*)d_ws;
  // ws layout (bytes): [0] loss_sum f32 | [256] counts i32[1024] |
  //                    [4352] wws f32[1024] | [8448] Whp f16[262144]  => 532736 total
  float* loss_sum = (float*)ws;
  int* counts = (int*)(ws + 256);
  float* wws = (float*)(ws + 4352);
  h16* Whp = (h16*)(ws + 8448);

  // loss_sum + counts zeroed by vq_wconv block 0 (one fewer dispatch)
  vq_wconv<<<512, 64, 0, stream>>>(W, Whp, wws, (int*)ws);
  vq_main<<<2048, 256, 0, stream>>>(X, Whp, wws, W, out, loss_sum, counts);
  vq_finalize<<<1, 256, 0, stream>>>(counts, loss_sum, out);
}

// Round 5
// 179.295 us; speedup vs baseline: 1.0180x; 1.0180x over previous
//
#include <hip/hip_runtime.h>

// VectorQuantizer: B=65536 rows, D=256, K=1024 codes.
// d_in[0] = inputs (B,D) fp32 ; d_in[1] = W (K,D) fp32
// d_out = [quantized_st (B*D)] [loss] [perplexity]  (fp32)
//
// R3 result: occupancy 41->72% with NO speedup => capped by a per-CU
// invariant: LDS A-read traffic (1.05M ds_read_b128, scattered-row
// pattern). R4: (1) X staged in MFMA-fragment order -> A-reads are dense
// lane-contiguous b128 (conflict-free); (2) nt=4 per wave -> each A-read
// feeds 4 MFMAs, halving LDS traffic; (3) nontemporal hints reverted
// (probe for the 97us bench-vs-kernel gap).
// (R5 = R4 resubmitted verbatim: container infra failure, kernel never ran.)

using h16   = _Float16;
using h16x8 = __attribute__((ext_vector_type(8))) _Float16;
using f32x4 = __attribute__((ext_vector_type(4))) float;

#define W_SCALE 1024.0f          // keep fp16 W out of denormal range
#define W_UNSCALE2 0.001953125f  // 2 / 1024, exact power of two
#define FRAG_H 520               // fragment stride in halves (512 + 8 pad -> ~4-way write conflict only)

// ---------------- kernel 1: pack W -> fp16 fragment-order + ||w||^2 + ws zero ----------------
// Packed layout: Whp[((tile*8 + ks)*64 + quad*16 + lm)*8 + j]
//   = W_scaled[code = tile*16 + lm][d = ks*32 + quad*8 + j]
__global__ __launch_bounds__(64) void vq_wconv(const float* __restrict__ W,
                                               h16* __restrict__ Whp,
                                               float* __restrict__ wws,
                                               int* __restrict__ zero_base) {
  const int t = threadIdx.x;
  if (blockIdx.x == 0) {
    // zero loss_sum (1 f32 @ 0) + counts (1024 i32 @ 256B): 1088 dwords over [0,4352)
#pragma unroll
    for (int i = t; i < 1088; i += 64) zero_base[i] = 0;
  }
  const int code = blockIdx.x * 2 + (t >> 5);  // 2 codes per block
  const int j = t & 31;                        // d-group of 8
  const int d0 = j * 8;
  f32x4 v0 = *(const f32x4*)(W + (size_t)code * 256 + d0);
  f32x4 v1 = *(const f32x4*)(W + (size_t)code * 256 + d0 + 4);
  h16x8 h;
  h[0] = (h16)(v0[0] * W_SCALE); h[1] = (h16)(v0[1] * W_SCALE);
  h[2] = (h16)(v0[2] * W_SCALE); h[3] = (h16)(v0[3] * W_SCALE);
  h[4] = (h16)(v1[0] * W_SCALE); h[5] = (h16)(v1[1] * W_SCALE);
  h[6] = (h16)(v1[2] * W_SCALE); h[7] = (h16)(v1[3] * W_SCALE);
  const int tile = code >> 4, ks = j >> 2, quad = j & 3, lm = code & 15;
  *(h16x8*)(Whp + (size_t)(((tile * 8 + ks) * 64 + quad * 16 + lm) * 8)) = h;
  float ss = v0[0] * v0[0] + v0[1] * v0[1] + v0[2] * v0[2] + v0[3] * v0[3]
           + v1[0] * v1[0] + v1[1] * v1[1] + v1[2] * v1[2] + v1[3] * v1[3];
#pragma unroll
  for (int m = 1; m <= 16; m <<= 1) ss += __shfl_xor(ss, m);  // within 32-lane half
  if (j == 0) wws[code] = ss;
}

// ---------------- kernel 2: fused scores + argmin + output + loss + histogram ----------------
// Block: 32 rows x all 1024 codes. 256 threads = 4 waves.
// Chunks=4; per chunk wave w covers n-tiles chunk*16 + w*4 + {0..3}.
// mfma_f32_16x16x32_f16: A[m=lm][k=quad*8+j], B[k=quad*8+j][n=lm],
//                        D[row=quad*4+reg][col=lm]
// Xs holds A-fragments in MFMA order: frag(mt,ks) at (mt*8+ks)*FRAG_H,
// element (quad*16+lm, j) at +(quad*16+lm)*8+j  -> K-loop A-read is
// lane-contiguous (conflict-free dense b128).
__global__ __launch_bounds__(256, 4) void vq_main(const float* __restrict__ X,
                                                  const h16* __restrict__ Whp,
                                                  const float* __restrict__ wws,
                                                  const float* __restrict__ W,
                                                  float* __restrict__ out,
                                                  float* __restrict__ loss_sum,
                                                  int* __restrict__ counts) {
  __shared__ h16 Xs[16 * FRAG_H];     // 16640 B (2 mt x 8 ks fragments)
  __shared__ float redS[4 * 32];      // 512 B
  __shared__ int redC[4 * 32];        // 512 B
  __shared__ int sIdx[32];            // 128 B
  __shared__ float xnorm[32];         // 128 B
  const int tid = threadIdx.x;
  const int lane = tid & 63;
  const int wid = tid >> 6;
  const int lm = lane & 15;
  const int quad = lane >> 4;
  const int rowBase = blockIdx.x * 32;

  // stage X tile (32 rows x 256 d, fp32 -> fp16, fragment-order) + fp32 ||x||^2.
  // 32 consecutive threads (one half-wave) cover one row.
#pragma unroll
  for (int it = 0; it < 4; ++it) {
    int q = it * 256 + tid;
    int r = q >> 5;            // row 0..31
    int dp = (q & 31) << 3;    // d-offset 0..248
    const float* src = X + (size_t)(rowBase + r) * 256 + dp;
    f32x4 v0 = *(const f32x4*)src;
    f32x4 v1 = *(const f32x4*)(src + 4);
    h16x8 h;
    h[0] = (h16)v0[0]; h[1] = (h16)v0[1]; h[2] = (h16)v0[2]; h[3] = (h16)v0[3];
    h[4] = (h16)v1[0]; h[5] = (h16)v1[1]; h[6] = (h16)v1[2]; h[7] = (h16)v1[3];
    int mt = r >> 4, lmr = r & 15, ksw = dp >> 5, qdw = (dp >> 3) & 3;
    *(h16x8*)(Xs + (mt * 8 + ksw) * FRAG_H + (qdw * 16 + lmr) * 8) = h;
    float ss = v0[0] * v0[0] + v0[1] * v0[1] + v0[2] * v0[2] + v0[3] * v0[3]
             + v1[0] * v1[0] + v1[1] * v1[1] + v1[2] * v1[2] + v1[3] * v1[3];
#pragma unroll
    for (int m = 1; m <= 16; m <<= 1) ss += __shfl_xor(ss, m);  // within the 32-lane half
    if ((q & 31) == 0) xnorm[r] = ss;
  }
  __syncthreads();  // the ONLY barrier before the reduce

  // running best per row-slot: slot = mt*4+reg -> row = mt*16 + quad*4 + reg
  float bestS[8];
  int bestC[8];
#pragma unroll
  for (int s = 0; s < 8; ++s) { bestS[s] = 3.4e38f; bestC[s] = 0x7fffffff; }

  for (int chunk = 0; chunk < 4; ++chunk) {
    const int tbase = chunk * 16 + wid * 4;  // this wave's first n-tile
    const h16* bp = Whp + (size_t)tbase * 4096 + lane * 8;
    float wn0 = wws[tbase * 16 + lm];        // hoisted: hide under MFMAs
    float wn1 = wws[tbase * 16 + 16 + lm];
    float wn2 = wws[tbase * 16 + 32 + lm];
    float wn3 = wws[tbase * 16 + 48 + lm];
    f32x4 acc[2][4];
#pragma unroll
    for (int mt = 0; mt < 2; ++mt)
#pragma unroll
      for (int nt = 0; nt < 4; ++nt) {
        f32x4 z = {0.0f, 0.0f, 0.0f, 0.0f};
        acc[mt][nt] = z;
      }

#pragma unroll 2
    for (int ks = 0; ks < 8; ++ks) {  // no barriers: B from L2, A from LDS
      h16x8 b0 = *(const h16x8*)(bp + ks * 512);
      h16x8 b1 = *(const h16x8*)(bp + ks * 512 + 4096);
      h16x8 b2 = *(const h16x8*)(bp + ks * 512 + 8192);
      h16x8 b3 = *(const h16x8*)(bp + ks * 512 + 12288);
      h16x8 a0 = *(const h16x8*)(Xs + ks * FRAG_H + lane * 8);
      h16x8 a1 = *(const h16x8*)(Xs + (8 + ks) * FRAG_H + lane * 8);
      acc[0][0] = __builtin_amdgcn_mfma_f32_16x16x32_f16(a0, b0, acc[0][0], 0, 0, 0);
      acc[0][1] = __builtin_amdgcn_mfma_f32_16x16x32_f16(a0, b1, acc[0][1], 0, 0, 0);
      acc[0][2] = __builtin_amdgcn_mfma_f32_16x16x32_f16(a0, b2, acc[0][2], 0, 0, 0);
      acc[0][3] = __builtin_amdgcn_mfma_f32_16x16x32_f16(a0, b3, acc[0][3], 0, 0, 0);
      acc[1][0] = __builtin_amdgcn_mfma_f32_16x16x32_f16(a1, b0, acc[1][0], 0, 0, 0);
      acc[1][1] = __builtin_amdgcn_mfma_f32_16x16x32_f16(a1, b1, acc[1][1], 0, 0, 0);
      acc[1][2] = __builtin_amdgcn_mfma_f32_16x16x32_f16(a1, b2, acc[1][2], 0, 0, 0);
      acc[1][3] = __builtin_amdgcn_mfma_f32_16x16x32_f16(a1, b3, acc[1][3], 0, 0, 0);
    }

    // epilogue: score = ||w||^2 - 2*dot ; fold into running best
#pragma unroll
    for (int nt = 0; nt < 4; ++nt) {
      int code = (tbase + nt) * 16 + lm;
      float wn = (nt == 0) ? wn0 : (nt == 1) ? wn1 : (nt == 2) ? wn2 : wn3;
#pragma unroll
      for (int mt = 0; mt < 2; ++mt)
#pragma unroll
        for (int reg = 0; reg < 4; ++reg) {
          float s = fmaf(-W_UNSCALE2, acc[mt][nt][reg], wn);
          int slot = mt * 4 + reg;
          if (s < bestS[slot]) { bestS[slot] = s; bestC[slot] = code; }
        }
    }
  }

  // reduce across the 16 lanes of each quad (same rows, different codes)
#pragma unroll
  for (int m = 1; m <= 8; m <<= 1) {
#pragma unroll
    for (int s = 0; s < 8; ++s) {
      float os = __shfl_xor(bestS[s], m);
      int oc = __shfl_xor(bestC[s], m);
      if (os < bestS[s] || (os == bestS[s] && oc < bestC[s])) { bestS[s] = os; bestC[s] = oc; }
    }
  }
  if (lm == 0) {
#pragma unroll
    for (int s = 0; s < 8; ++s) {
      int row = (s >> 2) * 16 + quad * 4 + (s & 3);
      redS[wid * 32 + row] = bestS[s];
      redC[wid * 32 + row] = bestC[s];
    }
  }
  __syncthreads();
  if (wid == 0) {  // wave 0: final argmin per row + histogram + loss
    float lossv = 0.0f;
    if (lane < 32) {
      float b = 3.4e38f;
      int c = 0x7fffffff;
#pragma unroll
      for (int w = 0; w < 4; ++w) {
        float s = redS[w * 32 + lane];
        int cc = redC[w * 32 + lane];
        if (s < b || (s == b && cc < c)) { b = s; c = cc; }
      }
      sIdx[lane] = c;
      atomicAdd(&counts[c], 1);
      // ||x - w||^2 = ||x||^2 + (||w||^2 - 2 x.w) = xnorm + bestScore
      lossv = xnorm[lane] + b;
    }
#pragma unroll
    for (int m = 1; m <= 32; m <<= 1) lossv += __shfl_xor(lossv, m);
    if (lane == 0) atomicAdd(loss_sum, lossv);
  }
  __syncthreads();

  // output phase: out row = W[idx] (== x + sg(q-x) numerically). Wave w: rows w*8..+7.
  const int d4 = lane << 2;
#pragma unroll 2
  for (int i = 0; i < 8; ++i) {
    int row = wid * 8 + i;
    int idx = sIdx[row];
    f32x4 qv = *(const f32x4*)(W + (size_t)idx * 256 + d4);
    *(f32x4*)(out + (size_t)(rowBase + row) * 256 + d4) = qv;
  }
}

// ---------------- kernel 3: loss + perplexity ----------------
__global__ __launch_bounds__(256) void vq_finalize(const int* __restrict__ counts,
                                                   const float* __restrict__ loss_sum,
                                                   float* __restrict__ out) {
  __shared__ float red[256];
  const int tid = threadIdx.x;
  float h = 0.0f;
#pragma unroll
  for (int k = tid; k < 1024; k += 256) {
    float p = (float)counts[k] * (1.0f / 65536.0f);
    h += p * logf(p + 1e-10f);
  }
  red[tid] = h;
  __syncthreads();
#pragma unroll
  for (int s = 128; s > 0; s >>= 1) {
    if (tid < s) red[tid] += red[tid + s];
    __syncthreads();
  }
  if (tid == 0) {
    out[16777216] = loss_sum[0] * (1.25f / 16777216.0f);  // (1+0.25)*mean((q-x)^2)
    out[16777217] = expf(-red[0]);
  }
}

// ---------------- launch ----------------
extern "C" void kernel_launch(void* const* d_in, const int* in_sizes, int n_in,
                              void* d_out, int out_size, void* d_ws, size_t ws_size,
                              hipStream_t stream) {
  (void)in_sizes; (void)n_in; (void)out_size; (void)ws_size;
  const float* X = (const float*)d_in[0];
  const float* W = (const float*)d_in[1];
  float* out = (float*)d_out;
  char* ws = (char*)d_ws;
  // ws layout (bytes): [0] loss_sum f32 | [256] counts i32[1024] |
  //                    [4352] wws f32[1024] | [8448] Whp f16[262144]  => 532736 total
  float* loss_sum = (float*)ws;
  int* counts = (int*)(ws + 256);
  float* wws = (float*)(ws + 4352);
  h16* Whp = (h16*)(ws + 8448);

  // loss_sum + counts zeroed by vq_wconv block 0 (one fewer dispatch)
  vq_wconv<<<512, 64, 0, stream>>>(W, Whp, wws, (int*)ws);
  vq_main<<<2048, 256, 0, stream>>>(X, Whp, wws, W, out, loss_sum, counts);
  vq_finalize<<<1, 256, 0, stream>>>(counts, loss_sum, out);
}

// Round 6
// 169.004 us; speedup vs baseline: 1.0800x; 1.0609x over previous
//
#include <hip/hip_runtime.h>

// VectorQuantizer: B=65536 rows, D=256, K=1024 codes.
// d_in[0] = inputs (B,D) fp32 ; d_in[1] = W (K,D) fp32
// d_out = [quantized_st (B*D)] [loss] [perplexity]  (fp32)
//
// Evidence R2/R3/R5: occupancy >16 waves/CU buys nothing; bank conflicts
// minor; the ranking tracks B-fragment L2 traffic per CU = (256/M)*512KB.
// R6: M=64 rows/block (2 MB/CU B-traffic, R2's best point) + fragment-
// ordered Xs (conflict-free lane-contiguous A-reads) + mt=4 B-reuse.
// LDS 35.8 KB -> 4 blocks/CU (16 waves/CU).

using h16   = _Float16;
using h16x8 = __attribute__((ext_vector_type(8))) _Float16;
using f32x4 = __attribute__((ext_vector_type(4))) float;

#define W_SCALE 1024.0f          // keep fp16 W out of denormal range
#define W_UNSCALE2 0.001953125f  // 2 / 1024, exact power of two
#define FRAG_H 520               // fragment stride in halves (512 + 8 pad; 1040B = 65*16B aligned)

// ---------------- kernel 1: pack W -> fp16 fragment-order + ||w||^2 + ws zero ----------------
// Packed layout: Whp[((tile*8 + ks)*64 + quad*16 + lm)*8 + j]
//   = W_scaled[code = tile*16 + lm][d = ks*32 + quad*8 + j]
__global__ __launch_bounds__(64) void vq_wconv(const float* __restrict__ W,
                                               h16* __restrict__ Whp,
                                               float* __restrict__ wws,
                                               int* __restrict__ zero_base) {
  const int t = threadIdx.x;
  if (blockIdx.x == 0) {
    // zero loss_sum (1 f32 @ 0) + counts (1024 i32 @ 256B): 1088 dwords over [0,4352)
#pragma unroll
    for (int i = t; i < 1088; i += 64) zero_base[i] = 0;
  }
  const int code = blockIdx.x * 2 + (t >> 5);  // 2 codes per block
  const int j = t & 31;                        // d-group of 8
  const int d0 = j * 8;
  f32x4 v0 = *(const f32x4*)(W + (size_t)code * 256 + d0);
  f32x4 v1 = *(const f32x4*)(W + (size_t)code * 256 + d0 + 4);
  h16x8 h;
  h[0] = (h16)(v0[0] * W_SCALE); h[1] = (h16)(v0[1] * W_SCALE);
  h[2] = (h16)(v0[2] * W_SCALE); h[3] = (h16)(v0[3] * W_SCALE);
  h[4] = (h16)(v1[0] * W_SCALE); h[5] = (h16)(v1[1] * W_SCALE);
  h[6] = (h16)(v1[2] * W_SCALE); h[7] = (h16)(v1[3] * W_SCALE);
  const int tile = code >> 4, ks = j >> 2, quad = j & 3, lm = code & 15;
  *(h16x8*)(Whp + (size_t)(((tile * 8 + ks) * 64 + quad * 16 + lm) * 8)) = h;
  float ss = v0[0] * v0[0] + v0[1] * v0[1] + v0[2] * v0[2] + v0[3] * v0[3]
           + v1[0] * v1[0] + v1[1] * v1[1] + v1[2] * v1[2] + v1[3] * v1[3];
#pragma unroll
  for (int m = 1; m <= 16; m <<= 1) ss += __shfl_xor(ss, m);  // within 32-lane half
  if (j == 0) wws[code] = ss;
}

// ---------------- kernel 2: fused scores + argmin + output + loss + histogram ----------------
// Block: 64 rows x all 1024 codes. 256 threads = 4 waves, 4 blocks/CU.
// Chunks=8; per chunk wave w covers n-tiles chunk*8 + w*2 + {0,1}.
// mfma_f32_16x16x32_f16: A[m=lm][k=quad*8+j], B[k=quad*8+j][n=lm],
//                        D[row=quad*4+reg][col=lm]
// Xs holds A-fragments in MFMA order: frag(mt,ks) at (mt*8+ks)*FRAG_H,
// element (quad*16+lm, j) at +lane*8  -> K-loop A-read is lane-contiguous
// (conflict-free dense b128). Each b-load feeds 4 MFMAs (mt reuse).
__global__ __launch_bounds__(256, 4) void vq_main(const float* __restrict__ X,
                                                  const h16* __restrict__ Whp,
                                                  const float* __restrict__ wws,
                                                  const float* __restrict__ W,
                                                  float* __restrict__ out,
                                                  float* __restrict__ loss_sum,
                                                  int* __restrict__ counts) {
  __shared__ h16 Xs[32 * FRAG_H];     // 33280 B (4 mt x 8 ks fragments)
  __shared__ float redS[4 * 64];      // 1 KB
  __shared__ int redC[4 * 64];        // 1 KB
  __shared__ int sIdx[64];            // 256 B
  __shared__ float xnorm[64];         // 256 B   (total 35840 B -> 4 blocks/CU)
  const int tid = threadIdx.x;
  const int lane = tid & 63;
  const int wid = tid >> 6;
  const int lm = lane & 15;
  const int quad = lane >> 4;
  const int rowBase = blockIdx.x * 64;

  // stage X tile (64 rows x 256 d, fp32 -> fp16, fragment-order) + fp32 ||x||^2.
  // 32 consecutive threads (one half-wave) cover one row.
#pragma unroll
  for (int it = 0; it < 8; ++it) {
    int q = it * 256 + tid;
    int r = q >> 5;            // row 0..63
    int dp = (q & 31) << 3;    // d-offset 0..248
    const float* src = X + (size_t)(rowBase + r) * 256 + dp;
    f32x4 v0 = *(const f32x4*)src;
    f32x4 v1 = *(const f32x4*)(src + 4);
    h16x8 h;
    h[0] = (h16)v0[0]; h[1] = (h16)v0[1]; h[2] = (h16)v0[2]; h[3] = (h16)v0[3];
    h[4] = (h16)v1[0]; h[5] = (h16)v1[1]; h[6] = (h16)v1[2]; h[7] = (h16)v1[3];
    int mt = r >> 4, lmr = r & 15, ksw = dp >> 5, qdw = (dp >> 3) & 3;
    *(h16x8*)(Xs + (mt * 8 + ksw) * FRAG_H + (qdw * 16 + lmr) * 8) = h;
    float ss = v0[0] * v0[0] + v0[1] * v0[1] + v0[2] * v0[2] + v0[3] * v0[3]
             + v1[0] * v1[0] + v1[1] * v1[1] + v1[2] * v1[2] + v1[3] * v1[3];
#pragma unroll
    for (int m = 1; m <= 16; m <<= 1) ss += __shfl_xor(ss, m);  // within the 32-lane half
    if ((q & 31) == 0) xnorm[r] = ss;
  }
  __syncthreads();  // the ONLY barrier before the reduce

  // running best per row-slot: slot = mt*4+reg -> row = mt*16 + quad*4 + reg
  float bestS[16];
  int bestC[16];
#pragma unroll
  for (int s = 0; s < 16; ++s) { bestS[s] = 3.4e38f; bestC[s] = 0x7fffffff; }

  for (int chunk = 0; chunk < 8; ++chunk) {
    const int tbase = chunk * 8 + wid * 2;  // this wave's first n-tile
    const h16* bp = Whp + (size_t)tbase * 4096 + lane * 8;
    float wn0 = wws[tbase * 16 + lm];        // hoisted: hide under MFMAs
    float wn1 = wws[tbase * 16 + 16 + lm];
    f32x4 acc[4][2];
#pragma unroll
    for (int mt = 0; mt < 4; ++mt)
#pragma unroll
      for (int nt = 0; nt < 2; ++nt) {
        f32x4 z = {0.0f, 0.0f, 0.0f, 0.0f};
        acc[mt][nt] = z;
      }

#pragma unroll 2
    for (int ks = 0; ks < 8; ++ks) {  // no barriers: B from L2, A from LDS
      h16x8 b0 = *(const h16x8*)(bp + ks * 512);         // n-tile tbase
      h16x8 b1 = *(const h16x8*)(bp + ks * 512 + 4096);  // n-tile tbase+1
#pragma unroll
      for (int mt = 0; mt < 4; ++mt) {
        h16x8 a = *(const h16x8*)(Xs + (mt * 8 + ks) * FRAG_H + lane * 8);
        acc[mt][0] = __builtin_amdgcn_mfma_f32_16x16x32_f16(a, b0, acc[mt][0], 0, 0, 0);
        acc[mt][1] = __builtin_amdgcn_mfma_f32_16x16x32_f16(a, b1, acc[mt][1], 0, 0, 0);
      }
    }

    // epilogue: score = ||w||^2 - 2*dot ; fold into running best
#pragma unroll
    for (int nt = 0; nt < 2; ++nt) {
      int code = (tbase + nt) * 16 + lm;
      float wn = nt ? wn1 : wn0;
#pragma unroll
      for (int mt = 0; mt < 4; ++mt)
#pragma unroll
        for (int reg = 0; reg < 4; ++reg) {
          float s = fmaf(-W_UNSCALE2, acc[mt][nt][reg], wn);
          int slot = mt * 4 + reg;
          if (s < bestS[slot]) { bestS[slot] = s; bestC[slot] = code; }
        }
    }
  }

  // reduce across the 16 lanes of each quad (same rows, different codes)
#pragma unroll
  for (int m = 1; m <= 8; m <<= 1) {
#pragma unroll
    for (int s = 0; s < 16; ++s) {
      float os = __shfl_xor(bestS[s], m);
      int oc = __shfl_xor(bestC[s], m);
      if (os < bestS[s] || (os == bestS[s] && oc < bestC[s])) { bestS[s] = os; bestC[s] = oc; }
    }
  }
  if (lm == 0) {
#pragma unroll
    for (int s = 0; s < 16; ++s) {
      int row = (s >> 2) * 16 + quad * 4 + (s & 3);
      redS[wid * 64 + row] = bestS[s];
      redC[wid * 64 + row] = bestC[s];
    }
  }
  __syncthreads();
  if (wid == 0) {  // wave 0: final argmin per row (64 rows = 64 lanes) + histogram + loss
    float b = 3.4e38f;
    int c = 0x7fffffff;
#pragma unroll
    for (int w = 0; w < 4; ++w) {
      float s = redS[w * 64 + lane];
      int cc = redC[w * 64 + lane];
      if (s < b || (s == b && cc < c)) { b = s; c = cc; }
    }
    sIdx[lane] = c;
    atomicAdd(&counts[c], 1);
    // ||x - w||^2 = ||x||^2 + (||w||^2 - 2 x.w) = xnorm + bestScore
    float lossv = xnorm[lane] + b;
#pragma unroll
    for (int m = 1; m <= 32; m <<= 1) lossv += __shfl_xor(lossv, m);
    if (lane == 0) atomicAdd(loss_sum, lossv);
  }
  __syncthreads();

  // output phase: out row = W[idx] (== x + sg(q-x) numerically). Wave w: rows w*16..+15.
  const int d4 = lane << 2;
#pragma unroll 2
  for (int i = 0; i < 16; ++i) {
    int row = wid * 16 + i;
    int idx = sIdx[row];
    f32x4 qv = *(const f32x4*)(W + (size_t)idx * 256 + d4);
    *(f32x4*)(out + (size_t)(rowBase + row) * 256 + d4) = qv;
  }
}

// ---------------- kernel 3: loss + perplexity ----------------
__global__ __launch_bounds__(256) void vq_finalize(const int* __restrict__ counts,
                                                   const float* __restrict__ loss_sum,
                                                   float* __restrict__ out) {
  __shared__ float red[256];
  const int tid = threadIdx.x;
  float h = 0.0f;
#pragma unroll
  for (int k = tid; k < 1024; k += 256) {
    float p = (float)counts[k] * (1.0f / 65536.0f);
    h += p * logf(p + 1e-10f);
  }
  red[tid] = h;
  __syncthreads();
#pragma unroll
  for (int s = 128; s > 0; s >>= 1) {
    if (tid < s) red[tid] += red[tid + s];
    __syncthreads();
  }
  if (tid == 0) {
    out[16777216] = loss_sum[0] * (1.25f / 16777216.0f);  // (1+0.25)*mean((q-x)^2)
    out[16777217] = expf(-red[0]);
  }
}

// ---------------- launch ----------------
extern "C" void kernel_launch(void* const* d_in, const int* in_sizes, int n_in,
                              void* d_out, int out_size, void* d_ws, size_t ws_size,
                              hipStream_t stream) {
  (void)in_sizes; (void)n_in; (void)out_size; (void)ws_size;
  const float* X = (const float*)d_in[0];
  const float* W = (const float*)d_in[1];
  float* out = (float*)d_out;
  char* ws = (char*)d_ws;
  // ws layout (bytes): [0] loss_sum f32 | [256] counts i32[1024] |
  //                    [4352] wws f32[1024] | [8448] Whp f16[262144]  => 532736 total
  float* loss_sum = (float*)ws;
  int* counts = (int*)(ws + 256);
  float* wws = (float*)(ws + 4352);
  h16* Whp = (h16*)(ws + 8448);

  // loss_sum + counts zeroed by vq_wconv block 0 (one fewer dispatch)
  vq_wconv<<<512, 64, 0, stream>>>(W, Whp, wws, (int*)ws);
  vq_main<<<1024, 256, 0, stream>>>(X, Whp, wws, W, out, loss_sum, counts);
  vq_finalize<<<1, 256, 0, stream>>>(counts, loss_sum, out);
}